// Round 2
// baseline (2643.571 us; speedup 1.0000x reference)
//
#include <hip/hip_runtime.h>
#include <hip/hip_bf16.h>
#include <cstdint>
#include <cstddef>

typedef __hip_bfloat16 bf16;

#define HDIM 256
#define H4   1024
#define NVOCAB 26

// ---- workspace layout (float offsets from (float*)d_ws) ----
// ws[0] (as int) = dtype flag: 1 = inputs are fp32, 0 = inputs are bf16
#define OFF_WIHT  16                    // [256][1024] W_ihT[k*1024+r] = W_ih[r][k]
#define OFF_WHHT  (OFF_WIHT+262144)     // [256][1024]
#define OFF_WC1T  (OFF_WHHT+262144)     // [256][256]  Wc1T[k*256+i] = Wc[i][k]
#define OFF_WTT   (OFF_WC1T+65536)      // [256][256]  WtT[k*256+i]  = Wt[i][k]
#define OFF_BSUM  (OFF_WTT+65536)       // [1024] b_ih + b_hh
#define OFF_HH1   (OFF_BSUM+1024)       // [1024] W_hh @ h1 + bsum
#define OFF_H1    (OFF_HH1+1024)        // [256]
#define OFF_C1    (OFF_H1+256)          // [256]
#define OFF_WCH1  (OFF_C1+256)          // [256]  Wc[:, :256] @ h1
#define OFF_BTF   (OFF_WCH1+256)        // [256]  bt fp32
#define OFF_EWC   (OFF_BTF+256)         // [26][256]  Wc[:,256:] @ emb[v] + bc
#define OFF_P8    (OFF_EWC+6656)        // [26][1024] W_ih @ out8[v]
#define OFF_SLABS (OFF_P8+26624)        // = 691728 floats -> byte 2766912
// slabA: 16384*256 bf16 (8.39 MB), slabB: 4096*256 bf16 (2.10 MB); total ~12.6 MB

__device__ __forceinline__ float sigmf(float x){ return 1.0f/(1.0f+__expf(-x)); }
__device__ __forceinline__ float tanhfast(float x){ return 1.0f - 2.0f/(__expf(2.0f*x)+1.0f); }

// dual-dtype input decode: f32 flag chosen at runtime by detect_kernel
__device__ __forceinline__ float ldin(const void* p, int i, int f32){
  if (f32) return ((const float*)p)[i];
  unsigned int w = ((unsigned int)((const unsigned short*)p)[i]) << 16;
  return __uint_as_float(w);
}

__device__ __forceinline__ float blockMax(float v, volatile float* rbuf, int tid){
  #pragma unroll
  for (int o=32;o>0;o>>=1) v = fmaxf(v, __shfl_xor(v,o,64));
  if ((tid&63)==0) rbuf[tid>>6]=v;
  __syncthreads();
  v = fmaxf(fmaxf(rbuf[0],rbuf[1]),fmaxf(rbuf[2],rbuf[3]));
  __syncthreads();
  return v;
}
__device__ __forceinline__ float blockSum(float v, volatile float* rbuf, int tid){
  #pragma unroll
  for (int o=32;o>0;o>>=1) v += __shfl_xor(v,o,64);
  if ((tid&63)==0) rbuf[tid>>6]=v;
  __syncthreads();
  v = (rbuf[0]+rbuf[1])+(rbuf[2]+rbuf[3]);
  __syncthreads();
  return v;
}

// ---- dtype detector: fp32 data read as halfwords has ~0.4% exp==0xFF patterns;
//      genuine bf16 N(0,0.0025) weights have none.
__global__ void detect_kernel(int* flag, const unsigned short* wih){
  __shared__ int cnt;
  if (threadIdx.x==0) cnt=0;
  __syncthreads();
  int c=0;
  for (int i=threadIdx.x;i<262144;i+=256){
    unsigned short h = wih[i];
    if ((h & 0x7F80u) == 0x7F80u) c++;
  }
  if (c) atomicAdd(&cnt, c);
  __syncthreads();
  if (threadIdx.x==0) flag[0] = (cnt>0) ? 1 : 0;
}

// ---- prep: transpose weights to fp32 tables, fold biases ----
__global__ __launch_bounds__(256) void prep_kernel(
    float* __restrict__ ws, const void* W_ih, const void* W_hh,
    const void* Wc, const void* Wt,
    const void* b_ih, const void* b_hh, const void* bt)
{
  const int f32 = ((const int*)ws)[0];
  int stride = gridDim.x*blockDim.x;
  int t0 = blockIdx.x*blockDim.x + threadIdx.x;
  for (int idx=t0; idx<262144; idx+=stride){
    int k = idx >> 10, r = idx & 1023;
    ws[OFF_WIHT+idx] = ldin(W_ih, r*HDIM+k, f32);
    ws[OFF_WHHT+idx] = ldin(W_hh, r*HDIM+k, f32);
  }
  for (int idx=t0; idx<65536; idx+=stride){
    int k = idx >> 8, i = idx & 255;
    ws[OFF_WC1T+idx] = ldin(Wc, i*512+k, f32);
    ws[OFF_WTT +idx] = ldin(Wt, i*HDIM+k, f32);
  }
  for (int idx=t0; idx<1024; idx+=stride)
    ws[OFF_BSUM+idx] = ldin(b_ih, idx, f32) + ldin(b_hh, idx, f32);
  for (int idx=t0; idx<256; idx+=stride)
    ws[OFF_BTF+idx] = ldin(bt, idx, f32);
}

// ---- EWc[v] = Wc[:,256:] @ emb[v] + bc ----
__global__ __launch_bounds__(256) void ewc_kernel(
    float* __restrict__ ws, const void* Wc, const void* bc, const void* emb)
{
  const int f32 = ((const int*)ws)[0];
  int v = blockIdx.x, i = threadIdx.x;
  __shared__ float se[HDIM];
  se[i] = ldin(emb, v*HDIM+i, f32);
  __syncthreads();
  float a = ldin(bc, i, f32);
  for (int k=0;k<HDIM;k++) a += ldin(Wc, i*512+256+k, f32) * se[k];
  ws[OFF_EWC + v*HDIM + i] = a;
}

// ---- global constants: h1,c1 (post step-0), hh1 = W_hh@h1+bsum, WcH1 ----
__global__ __launch_bounds__(256) void const_kernel(float* __restrict__ ws, const void* linit)
{
  const int f32 = ((const int*)ws)[0];
  int tid = threadIdx.x;
  __shared__ float sx[HDIM];
  __shared__ float shh[HDIM];
  sx[tid] = ldin(linit, tid, f32);
  __syncthreads();
  float acc[4];
  #pragma unroll
  for (int g=0;g<4;g++) acc[g] = ws[OFF_BSUM+g*HDIM+tid];
  for (int k=0;k<HDIM;k++){
    float xv = sx[k];
    #pragma unroll
    for (int g=0;g<4;g++) acc[g] += ws[OFF_WIHT + k*H4 + g*HDIM + tid]*xv;
  }
  float iv=sigmf(acc[0]), gv=tanhfast(acc[2]), ov=sigmf(acc[3]);
  float c1 = iv*gv;                  // c0 = 0 -> forget term vanishes
  float h1 = ov*tanhfast(c1);
  ws[OFF_H1+tid]=h1; ws[OFF_C1+tid]=c1;
  shh[tid]=h1;
  __syncthreads();
  float a2[4];
  #pragma unroll
  for (int g=0;g<4;g++) a2[g] = ws[OFF_BSUM+g*HDIM+tid];
  float ac = 0.f;
  for (int k=0;k<HDIM;k++){
    float hv = shh[k];
    #pragma unroll
    for (int g=0;g<4;g++) a2[g] += ws[OFF_WHHT + k*H4 + g*HDIM + tid]*hv;
    ac += ws[OFF_WC1T + k*HDIM + tid]*hv;
  }
  #pragma unroll
  for (int g=0;g<4;g++) ws[OFF_HH1+g*HDIM+tid]=a2[g];
  ws[OFF_WCH1+tid]=ac;
}

// ---- level-8 collapses to 26 entries; P8[v] = W_ih @ log_softmax(tag_v) ----
__global__ __launch_bounds__(256) void table_kernel(float* __restrict__ ws)
{
  int v = blockIdx.x, tid = threadIdx.x;
  __shared__ float scomb[HDIM];
  __shared__ float sout[HDIM];
  __shared__ float rbuf[4];
  scomb[tid] = ws[OFF_WCH1+tid] + ws[OFF_EWC + v*HDIM + tid];
  __syncthreads();
  float tg = ws[OFF_BTF+tid];
  for (int k=0;k<HDIM;k++) tg += ws[OFF_WTT + k*HDIM + tid]*scomb[k];
  float m = blockMax(tg, rbuf, tid);
  float e = __expf(tg-m);
  float s = blockSum(e, rbuf, tid);
  sout[tid] = tg - m - __logf(s);
  __syncthreads();
  float acc[4]={0.f,0.f,0.f,0.f};
  for (int k=0;k<HDIM;k++){
    float ov = sout[k];
    #pragma unroll
    for (int g=0;g<4;g++) acc[g] += ws[OFF_WIHT + k*H4 + g*HDIM + tid]*ov;
  }
  #pragma unroll
  for (int g=0;g<4;g++) ws[OFF_P8 + v*H4 + g*HDIM + tid] = acc[g];
}

// ---- per-level: B nodes per 256-thread block; consumers project child outs ----
template<int B, bool GATHER, bool LAST>
__global__ __launch_bounds__(256) void level_kernel(
    const float* __restrict__ ws, const bf16* __restrict__ OutPrev,
    const int* __restrict__ idents, int offL, int offC,
    bf16* __restrict__ OutNext, void* __restrict__ dout)
{
  __shared__ __align__(16) float sh[B][HDIM];   // h state per node
  __shared__ __align__(16) float sx[B][HDIM];   // child input per node
  __shared__ float rbuf[4];
  __shared__ int sid[B];
  const int tid = threadIdx.x;
  const int j0  = blockIdx.x * B;

  if (tid < B) sid[tid] = idents[offL + j0 + tid];

  const float* W_ihT = ws + OFF_WIHT;
  const float* W_hhT = ws + OFF_WHHT;
  const float* Wc1T  = ws + OFF_WC1T;
  const float* WtT   = ws + OFF_WTT;

  float h1v = ws[OFF_H1+tid];
  float c1v = ws[OFF_C1+tid];
  float creg[B];
  #pragma unroll
  for (int b=0;b<B;b++){ sh[b][tid]=h1v; creg[b]=c1v; }

  float bs[4], hh1r[4];
  #pragma unroll
  for (int g=0;g<4;g++){ bs[g]=ws[OFF_BSUM+g*HDIM+tid]; hh1r[g]=ws[OFF_HH1+g*HDIM+tid]; }
  __syncthreads();

  for (int t=1;t<=4;t++){
    if (!GATHER){
      #pragma unroll
      for (int b=0;b<B;b++)
        sx[b][tid] = __bfloat162float(OutPrev[(size_t)((j0+b)*4+(t-1))*HDIM + tid]);
    }
    __syncthreads();

    float acc[4][B];
    #pragma unroll
    for (int g=0;g<4;g++)
      #pragma unroll
      for (int b=0;b<B;b++) acc[g][b] = (t==1) ? hh1r[g] : bs[g];

    if (GATHER){
      #pragma unroll
      for (int b=0;b<B;b++){
        int id = idents[offC + (j0+b)*4 + (t-1)];
        const float* p = ws + OFF_P8 + (size_t)id*H4;
        #pragma unroll
        for (int g=0;g<4;g++) acc[g][b] += p[g*HDIM+tid];
      }
    } else {
      for (int k=0;k<HDIM;k+=4){
        float w[4][4];
        #pragma unroll
        for (int kk=0;kk<4;kk++)
          #pragma unroll
          for (int g=0;g<4;g++) w[kk][g]=W_ihT[(k+kk)*H4 + g*HDIM + tid];
        #pragma unroll
        for (int b=0;b<B;b++){
          float4 xv = *(const float4*)&sx[b][k];
          #pragma unroll
          for (int g=0;g<4;g++)
            acc[g][b] += w[0][g]*xv.x + w[1][g]*xv.y + w[2][g]*xv.z + w[3][g]*xv.w;
        }
      }
    }
    if (t>1){
      for (int k=0;k<HDIM;k+=4){
        float w[4][4];
        #pragma unroll
        for (int kk=0;kk<4;kk++)
          #pragma unroll
          for (int g=0;g<4;g++) w[kk][g]=W_hhT[(k+kk)*H4 + g*HDIM + tid];
        #pragma unroll
        for (int b=0;b<B;b++){
          float4 hv = *(const float4*)&sh[b][k];
          #pragma unroll
          for (int g=0;g<4;g++)
            acc[g][b] += w[0][g]*hv.x + w[1][g]*hv.y + w[2][g]*hv.z + w[3][g]*hv.w;
        }
      }
    }
    __syncthreads();
    #pragma unroll
    for (int b=0;b<B;b++){
      float iv=sigmf(acc[0][b]), fv=sigmf(acc[1][b]);
      float gv=tanhfast(acc[2][b]), ov=sigmf(acc[3][b]);
      float cn = fv*creg[b] + iv*gv;
      creg[b]=cn;
      sh[b][tid]=ov*tanhfast(cn);
    }
  }
  __syncthreads();

  // combined = Wc[:, :256] @ h_last + EWc[id]
  float accC[B];
  #pragma unroll
  for (int b=0;b<B;b++) accC[b]=0.f;
  for (int k=0;k<HDIM;k+=4){
    float w[4];
    #pragma unroll
    for (int kk=0;kk<4;kk++) w[kk]=Wc1T[(k+kk)*HDIM+tid];
    #pragma unroll
    for (int b=0;b<B;b++){
      float4 hv = *(const float4*)&sh[b][k];
      accC[b] += w[0]*hv.x + w[1]*hv.y + w[2]*hv.z + w[3]*hv.w;
    }
  }
  __syncthreads();
  #pragma unroll
  for (int b=0;b<B;b++) sh[b][tid] = accC[b] + ws[OFF_EWC + (size_t)sid[b]*HDIM + tid];
  __syncthreads();

  // tag = Wt @ combined + bt
  float tg[B];
  #pragma unroll
  for (int b=0;b<B;b++) tg[b]=ws[OFF_BTF+tid];
  for (int k=0;k<HDIM;k+=4){
    float w[4];
    #pragma unroll
    for (int kk=0;kk<4;kk++) w[kk]=WtT[(k+kk)*HDIM+tid];
    #pragma unroll
    for (int b=0;b<B;b++){
      float4 cv = *(const float4*)&sh[b][k];
      tg[b] += w[0]*cv.x + w[1]*cv.y + w[2]*cv.z + w[3]*cv.w;
    }
  }
  __syncthreads();

  float outv[B];
  #pragma unroll
  for (int b=0;b<B;b++){
    float m = blockMax(tg[b], rbuf, tid);
    float e = __expf(tg[b]-m);
    float s = blockSum(e, rbuf, tid);
    outv[b] = tg[b] - m - __logf(s);
  }
  if (LAST){
    const int f32 = ((const int*)ws)[0];
    if (f32) ((float*)dout)[tid] = outv[0];
    else     ((bf16*)dout)[tid]  = __float2bfloat16(outv[0]);
    return;
  }
  #pragma unroll
  for (int b=0;b<B;b++)
    OutNext[(size_t)(j0+b)*HDIM + tid] = __float2bfloat16(outv[b]);
}

extern "C" void kernel_launch(void* const* d_in, const int* in_sizes, int n_in,
                              void* d_out, int out_size, void* d_ws, size_t ws_size,
                              hipStream_t stream)
{
  (void)in_sizes; (void)n_in; (void)out_size; (void)ws_size;
  const int* idents = (const int*)d_in[0];
  const void* emb   = d_in[1];
  const void* W_ih  = d_in[2];
  const void* W_hh  = d_in[3];
  const void* b_ih  = d_in[4];
  const void* b_hh  = d_in[5];
  const void* Wc    = d_in[6];
  const void* bc    = d_in[7];
  const void* Wt    = d_in[8];
  const void* bt    = d_in[9];
  const void* linit = d_in[10];

  float* ws = (float*)d_ws;
  bf16* slabA = (bf16*)(ws + OFF_SLABS);
  bf16* slabB = slabA + (size_t)16384*HDIM;

  detect_kernel<<<1, 256, 0, stream>>>((int*)d_ws, (const unsigned short*)W_ih);
  prep_kernel <<<512, 256, 0, stream>>>(ws, W_ih, W_hh, Wc, Wt, b_ih, b_hh, bt);
  ewc_kernel  <<<NVOCAB, 256, 0, stream>>>(ws, Wc, bc, emb);
  const_kernel<<<1, 256, 0, stream>>>(ws, linit);
  table_kernel<<<NVOCAB, 256, 0, stream>>>(ws);

  // levels 7..0 ; idents offsets (4^l-1)/3 ; ping-pong out slabs
  level_kernel<8,true ,false><<<2048,256,0,stream>>>(ws, nullptr, idents, 5461, 21845, slabA, nullptr);
  level_kernel<8,false,false><<<512 ,256,0,stream>>>(ws, slabA,   idents, 1365, 0,     slabB, nullptr);
  level_kernel<8,false,false><<<128 ,256,0,stream>>>(ws, slabB,   idents, 341,  0,     slabA, nullptr);
  level_kernel<8,false,false><<<32  ,256,0,stream>>>(ws, slabA,   idents, 85,   0,     slabB, nullptr);
  level_kernel<8,false,false><<<8   ,256,0,stream>>>(ws, slabB,   idents, 21,   0,     slabA, nullptr);
  level_kernel<8,false,false><<<2   ,256,0,stream>>>(ws, slabA,   idents, 5,    0,     slabB, nullptr);
  level_kernel<4,false,false><<<1   ,256,0,stream>>>(ws, slabB,   idents, 1,    0,     slabA, nullptr);
  level_kernel<1,false,true ><<<1   ,256,0,stream>>>(ws, slabA,   idents, 0,    0,     nullptr, d_out);
}

// Round 3
// 1828.084 us; speedup vs baseline: 1.4461x; 1.4461x over previous
//
#include <hip/hip_runtime.h>
#include <hip/hip_bf16.h>
#include <cstdint>
#include <cstddef>

typedef __hip_bfloat16 bf16;
typedef unsigned short ushort;
typedef __attribute__((ext_vector_type(8))) short bf16x8;
typedef __attribute__((ext_vector_type(4))) float f32x4;

#define HDIM 256
#define NVOCAB 26

// ---- workspace layout (float offsets) ----
// int flags at wsf[0..3]: [1] = nonfinite-halfword count (>0 -> inputs are fp32)
#define OFF_BSUM  16                    // [1024] b_ih+b_hh
#define OFF_Z1    (OFF_BSUM+1024)       // [1024] step-0 preactivation
#define OFF_HH1   (OFF_Z1+1024)         // [1024] W_hh@h1 + bsum
#define OFF_H1    (OFF_HH1+1024)        // [256]
#define OFF_C1    (OFF_H1+256)          // [256]
#define OFF_WCH1  (OFF_C1+256)          // [256] Wc[:, :256]@h1
#define OFF_BTF   (OFF_WCH1+256)        // [256]
#define OFF_EWC   (OFF_BTF+256)         // [26][256] Wc[:,256:]@emb[v]+bc
#define OFF_P8    (OFF_EWC+6656)        // [26][1024] W_ih@out8[v]
#define OFF_FRAG  (OFF_P8+26624)        // ushort frag tables
// frag tables (ushort counts): FWIH 262144, FWHH 262144, FWC1 65536, FWT 65536
#define OFF_SLABS (OFF_FRAG+327680)     // ushort slabs: A=16384*256, B=4096*256

__device__ __forceinline__ float sigmf(float x){ return 1.0f/(1.0f+__expf(-x)); }
__device__ __forceinline__ float tanhfast(float x){ return 1.0f - 2.0f/(__expf(2.0f*x)+1.0f); }
__device__ __forceinline__ ushort f2b(float x){ bf16 h = __float2bfloat16(x); return *(ushort*)&h; }
__device__ __forceinline__ float ldin(const void* p, int i, int f32){
  if (f32) return ((const float*)p)[i];
  unsigned int w = ((unsigned int)((const ushort*)p)[i]) << 16;
  return __uint_as_float(w);
}

__device__ __forceinline__ float blockMax(float v, volatile float* rbuf, int tid){
  #pragma unroll
  for (int o=32;o>0;o>>=1) v = fmaxf(v, __shfl_xor(v,o,64));
  if ((tid&63)==0) rbuf[tid>>6]=v;
  __syncthreads();
  v = fmaxf(fmaxf(rbuf[0],rbuf[1]),fmaxf(rbuf[2],rbuf[3]));
  __syncthreads();
  return v;
}
__device__ __forceinline__ float blockSum(float v, volatile float* rbuf, int tid){
  #pragma unroll
  for (int o=32;o>0;o>>=1) v += __shfl_xor(v,o,64);
  if ((tid&63)==0) rbuf[tid>>6]=v;
  __syncthreads();
  v = (rbuf[0]+rbuf[1])+(rbuf[2]+rbuf[3]);
  __syncthreads();
  return v;
}

// ---- zero the flag words ----
__global__ void init_kernel(int* wsI){ if (threadIdx.x<4) wsI[threadIdx.x]=0; }

// ---- dtype detect: fp32 read as halfwords -> ~0.4% exp==0xFF halfwords ----
__global__ __launch_bounds__(256) void detect_kernel(int* wsI, const ushort* wih){
  int c=0;
  for (int i = blockIdx.x*blockDim.x + threadIdx.x; i < 262144; i += gridDim.x*blockDim.x){
    ushort h = wih[i];
    if ((h & 0x7F80u) == 0x7F80u) c++;
  }
  #pragma unroll
  for (int o=32;o>0;o>>=1) c += __shfl_xor(c,o,64);
  if ((threadIdx.x&63)==0 && c) atomicAdd(&wsI[1], c);
}

// ---- z1 = bsum + W_ih@linit ; also stash bsum, btf ----
__global__ __launch_bounds__(256) void z1_kernel(
    float* __restrict__ wsf, const void* W_ih, const void* b_ih, const void* b_hh,
    const void* bt, const void* linit)
{
  const int f32 = ((const int*)wsf)[1] != 0;
  __shared__ float sx[256];
  int tid = threadIdx.x;
  int r = blockIdx.x*256 + tid;
  sx[tid] = ldin(linit, tid, f32);
  __syncthreads();
  float a = ldin(b_ih, r, f32) + ldin(b_hh, r, f32);
  wsf[OFF_BSUM + r] = a;
  float z = a;
  for (int k=0;k<256;k++) z += ldin(W_ih, r*256+k, f32)*sx[k];
  wsf[OFF_Z1 + r] = z;
  if (blockIdx.x==0) wsf[OFF_BTF + tid] = ldin(bt, tid, f32);
}

// ---- h1,c1 from z1 ----
__global__ __launch_bounds__(256) void h1_kernel(float* __restrict__ wsf){
  int e = threadIdx.x;
  float zi = wsf[OFF_Z1+e], zg = wsf[OFF_Z1+512+e], zo = wsf[OFF_Z1+768+e];
  float c1 = sigmf(zi)*tanhfast(zg);     // c0=0 -> forget term vanishes
  float h1 = sigmf(zo)*tanhfast(c1);
  wsf[OFF_H1+e]=h1; wsf[OFF_C1+e]=c1;
}

// ---- hh1 = bsum + W_hh@h1 (blocks 0..3) ; wch1 = Wc1@h1 (block 4) ----
__global__ __launch_bounds__(256) void hh1_kernel(float* __restrict__ wsf, const void* W_hh, const void* Wc){
  const int f32 = ((const int*)wsf)[1] != 0;
  __shared__ float sh1[256];
  int tid = threadIdx.x;
  sh1[tid] = wsf[OFF_H1+tid];
  __syncthreads();
  if (blockIdx.x < 4){
    int r = blockIdx.x*256 + tid;
    float z = wsf[OFF_BSUM + r];
    for (int k=0;k<256;k++) z += ldin(W_hh, r*256+k, f32)*sh1[k];
    wsf[OFF_HH1 + r] = z;
  } else {
    float a = 0.f;
    for (int k=0;k<256;k++) a += ldin(Wc, tid*512+k, f32)*sh1[k];
    wsf[OFF_WCH1 + tid] = a;
  }
}

// ---- EWc[v] = Wc[:,256:]@emb[v] + bc ----
__global__ __launch_bounds__(256) void ewc_kernel(
    float* __restrict__ wsf, const void* Wc, const void* bc, const void* emb)
{
  const int f32 = ((const int*)wsf)[1] != 0;
  int v = blockIdx.x, i = threadIdx.x;
  __shared__ float se[256];
  se[i] = ldin(emb, v*256+i, f32);
  __syncthreads();
  float a = ldin(bc, i, f32);
  for (int k=0;k<256;k++) a += ldin(Wc, i*512+256+k, f32)*se[k];
  wsf[OFF_EWC + v*256 + i] = a;
}

// ---- build MFMA A-fragment tables (bf16) ----
// chunk c, lane L, j: m = mt*16+(L&15), k = ks*32+(L>>4)*8+j ; chunk=(mt*8+ks)
__global__ __launch_bounds__(256) void prep_kernel(
    float* __restrict__ wsf, const void* W_ih, const void* W_hh, const void* Wc, const void* Wt)
{
  const int f32 = ((const int*)wsf)[1] != 0;
  ushort* FWIH = (ushort*)(wsf + OFF_FRAG);
  ushort* FWHH = FWIH + 262144;
  ushort* FWC1 = FWHH + 262144;
  ushort* FWT  = FWC1 + 65536;
  int stride = gridDim.x*blockDim.x;
  int t0 = blockIdx.x*blockDim.x + threadIdx.x;
  for (int idx=t0; idx<262144; idx+=stride){
    int c = idx>>9, r = idx&511, L = r>>3, j = r&7;
    int mt = c>>3, ks = c&7;
    int m = (mt<<4) | (L&15);
    int k = (ks<<5) + ((L>>4)<<3) + j;
    FWIH[idx] = f2b(ldin(W_ih, m*256+k, f32));
    FWHH[idx] = f2b(ldin(W_hh, m*256+k, f32));
  }
  for (int idx=t0; idx<65536; idx+=stride){
    int c = idx>>9, r = idx&511, L = r>>3, j = r&7;
    int mt = c>>3, ks = c&7;
    int m = (mt<<4) | (L&15);
    int k = (ks<<5) + ((L>>4)<<3) + j;
    FWC1[idx] = f2b(ldin(Wc, m*512+k, f32));
    FWT [idx] = f2b(ldin(Wt, m*256+k, f32));
  }
}

// ---- level-8 table: out8[v] (26 entries), P8[v] = W_ih@out8[v] ----
__global__ __launch_bounds__(256) void table_kernel(float* __restrict__ wsf, const void* Wt, const void* W_ih){
  const int f32 = ((const int*)wsf)[1] != 0;
  int v = blockIdx.x, tid = threadIdx.x;
  __shared__ float scomb[256], sout[256], rbuf[4];
  scomb[tid] = wsf[OFF_WCH1+tid] + wsf[OFF_EWC + v*256 + tid];
  __syncthreads();
  float tg = wsf[OFF_BTF+tid];
  for (int k=0;k<256;k++) tg += ldin(Wt, tid*256+k, f32)*scomb[k];
  float m = blockMax(tg, rbuf, tid);
  float e = __expf(tg-m);
  float s = blockSum(e, rbuf, tid);
  sout[tid] = tg - m - __logf(s);
  __syncthreads();
  #pragma unroll
  for (int g=0; g<4; g++){
    float a = 0.f;
    for (int k=0;k<256;k++) a += ldin(W_ih, (g*256+tid)*256+k, f32)*sout[k];
    wsf[OFF_P8 + v*1024 + g*256 + tid] = a;
  }
}

// ---- MFMA level kernel: 16 nodes/block (N=16), 4 waves, wave w owns elements
//      e in [w*64, w*64+64) for ALL 4 gates (m-tile = g*16 + w*4 + q) ----
template<bool GATHER, bool LAST>
__global__ __launch_bounds__(256) void level_kernel(
    const float* __restrict__ wsf, const ushort* __restrict__ OutPrev,
    const int* __restrict__ idents, int offL, int offC, int nNodes,
    ushort* __restrict__ OutNext, void* __restrict__ dout)
{
  __shared__ __align__(16) ushort Hlds[16*264];
  __shared__ __align__(16) ushort Xlds[16*264];
  __shared__ __align__(16) float  Tlds[16*264];
  __shared__ float sBsum[1024], sHh1[1024], sC1[256], sBt[256];
  __shared__ int sid[16], sid4[64];

  const int tid  = threadIdx.x;
  const int wv   = tid >> 6;
  const int lane = tid & 63;
  const int ln15 = lane & 15;
  const int quad = lane >> 4;
  const int j0   = blockIdx.x * 16;

  const ushort* FWIH = (const ushort*)(wsf + OFF_FRAG);
  const ushort* FWHH = FWIH + 262144;
  const ushort* FWC1 = FWHH + 262144;
  const ushort* FWT  = FWC1 + 65536;
  const float*  P8   = wsf + OFF_P8;
  const float*  EWcP = wsf + OFF_EWC;

  for (int i=tid; i<1024; i+=256){ sBsum[i]=wsf[OFF_BSUM+i]; sHh1[i]=wsf[OFF_HH1+i]; }
  if (tid<256){ sC1[tid]=wsf[OFF_C1+tid]; sBt[tid]=wsf[OFF_BTF+tid]; }
  if (tid<16){ int nd = j0+tid; if (nd>=nNodes) nd=nNodes-1; sid[tid]=idents[offL+nd]; }
  if (GATHER && tid<64) sid4[tid] = idents[offC + j0*4 + tid];

  float creg[16];

  for (int t=1; t<=4; t++){
    if (!GATHER){
      for (int i=tid; i<512; i+=256){
        int n = i>>5, off = i&31;
        int node = j0+n; if (node>=nNodes) node=nNodes-1;
        uint4 v = ((const uint4*)OutPrev)[(size_t)(node*4 + (t-1))*32 + off];
        *(uint4*)&Xlds[n*264 + off*8] = v;
      }
    }
    __syncthreads();   // Xlds staged; previous combine's Hlds writes visible

    f32x4 acc[16];
    #pragma unroll
    for (int i=0;i<16;i++) acc[i] = (f32x4){0.f,0.f,0.f,0.f};

    if (t>=2 || !GATHER){
      for (int ks=0; ks<8; ks++){
        bf16x8 bh, bx;
        if (t>=2)    bh = *(const bf16x8*)&Hlds[ln15*264 + ks*32 + quad*8];
        if (!GATHER) bx = *(const bf16x8*)&Xlds[ln15*264 + ks*32 + quad*8];
        #pragma unroll
        for (int g=0; g<4; g++){
          #pragma unroll
          for (int q=0; q<4; q++){
            int mt = g*16 + wv*4 + q;
            int base = ((mt*8+ks)<<9) + (lane<<3);
            if (t>=2){
              bf16x8 a = *(const bf16x8*)&FWHH[base];
              acc[g*4+q] = __builtin_amdgcn_mfma_f32_16x16x32_bf16(a, bh, acc[g*4+q], 0,0,0);
            }
            if (!GATHER){
              bf16x8 a = *(const bf16x8*)&FWIH[base];
              acc[g*4+q] = __builtin_amdgcn_mfma_f32_16x16x32_bf16(a, bx, acc[g*4+q], 0,0,0);
            }
          }
        }
      }
    }
    __syncthreads();   // all Hlds/Xlds reads done

    const float* basev = (t==1) ? sHh1 : sBsum;
    const float* pg = nullptr;
    if (GATHER) pg = P8 + (size_t)sid4[ln15*4 + (t-1)]*1024;
    #pragma unroll
    for (int q=0; q<4; q++){
      #pragma unroll
      for (int r=0; r<4; r++){
        int e = wv*64 + q*16 + quad*4 + r;
        float x0=0.f,x1=0.f,x2=0.f,x3=0.f;
        if (GATHER){ x0=pg[e]; x1=pg[256+e]; x2=pg[512+e]; x3=pg[768+e]; }
        float zi = acc[0*4+q][r] + basev[e]       + x0;
        float zf = acc[1*4+q][r] + basev[256+e]   + x1;
        float zg = acc[2*4+q][r] + basev[512+e]   + x2;
        float zo = acc[3*4+q][r] + basev[768+e]   + x3;
        float cp = (t==1) ? sC1[e] : creg[q*4+r];
        float cn = sigmf(zf)*cp + sigmf(zi)*tanhfast(zg);
        creg[q*4+r] = cn;
        float h = sigmf(zo)*tanhfast(cn);
        Hlds[ln15*264 + e] = f2b(h);
      }
    }
  }
  __syncthreads();   // h5 staged

  // combined = Wc1 @ h5 + EWc[id]   (M=256: wave w owns m-tiles w*4..w*4+3)
  {
    f32x4 accC[4];
    #pragma unroll
    for (int q=0;q<4;q++) accC[q] = (f32x4){0.f,0.f,0.f,0.f};
    for (int ks=0; ks<8; ks++){
      bf16x8 b = *(const bf16x8*)&Hlds[ln15*264 + ks*32 + quad*8];
      #pragma unroll
      for (int q=0;q<4;q++){
        bf16x8 a = *(const bf16x8*)&FWC1[(((wv*4+q)*8+ks)<<9) + (lane<<3)];
        accC[q] = __builtin_amdgcn_mfma_f32_16x16x32_bf16(a, b, accC[q], 0,0,0);
      }
    }
    #pragma unroll
    for (int q=0;q<4;q++){
      #pragma unroll
      for (int r=0;r<4;r++){
        int m = wv*64 + q*16 + quad*4 + r;
        float cmb = accC[q][r] + EWcP[(size_t)sid[ln15]*256 + m];
        Xlds[ln15*264 + m] = f2b(cmb);
      }
    }
  }
  __syncthreads();

  // tag = Wt @ combined + bt
  {
    f32x4 accT[4];
    #pragma unroll
    for (int q=0;q<4;q++) accT[q] = (f32x4){0.f,0.f,0.f,0.f};
    for (int ks=0; ks<8; ks++){
      bf16x8 b = *(const bf16x8*)&Xlds[ln15*264 + ks*32 + quad*8];
      #pragma unroll
      for (int q=0;q<4;q++){
        bf16x8 a = *(const bf16x8*)&FWT[(((wv*4+q)*8+ks)<<9) + (lane<<3)];
        accT[q] = __builtin_amdgcn_mfma_f32_16x16x32_bf16(a, b, accT[q], 0,0,0);
      }
    }
    #pragma unroll
    for (int q=0;q<4;q++){
      #pragma unroll
      for (int r=0;r<4;r++){
        int m = wv*64 + q*16 + quad*4 + r;
        Tlds[ln15*264 + m] = accT[q][r] + sBt[m];
      }
    }
  }
  __syncthreads();

  // log-softmax per node; 16 threads per node, thread j owns e=[j*16, j*16+16)
  {
    int n = tid >> 4, j = tid & 15;
    float mx = -3.0e38f;
    #pragma unroll
    for (int i=0;i<16;i++) mx = fmaxf(mx, Tlds[n*264 + j*16 + i]);
    #pragma unroll
    for (int o=1;o<16;o<<=1) mx = fmaxf(mx, __shfl_xor(mx, o, 64));
    float s = 0.f;
    #pragma unroll
    for (int i=0;i<16;i++) s += __expf(Tlds[n*264 + j*16 + i] - mx);
    #pragma unroll
    for (int o=1;o<16;o<<=1) s += __shfl_xor(s, o, 64);
    float lz = mx + __logf(s);
    int node = j0 + n;
    if (LAST){
      if (n==0){
        const int f32o = ((const int*)wsf)[1] != 0;
        #pragma unroll
        for (int i=0;i<16;i++){
          int e = j*16+i;
          float v = Tlds[n*264 + e] - lz;
          if (f32o) ((float*)dout)[e] = v;
          else      ((ushort*)dout)[e] = f2b(v);
        }
      }
    } else if (node < nNodes){
      #pragma unroll
      for (int i=0;i<16;i++){
        int e = j*16+i;
        OutNext[(size_t)node*256 + e] = f2b(Tlds[n*264 + e] - lz);
      }
    }
  }
}

extern "C" void kernel_launch(void* const* d_in, const int* in_sizes, int n_in,
                              void* d_out, int out_size, void* d_ws, size_t ws_size,
                              hipStream_t stream)
{
  (void)in_sizes; (void)n_in; (void)out_size; (void)ws_size;
  const int* idents = (const int*)d_in[0];
  const void* emb   = d_in[1];
  const void* W_ih  = d_in[2];
  const void* W_hh  = d_in[3];
  const void* b_ih  = d_in[4];
  const void* b_hh  = d_in[5];
  const void* Wc    = d_in[6];
  const void* bc    = d_in[7];
  const void* Wt    = d_in[8];
  const void* bt    = d_in[9];
  const void* linit = d_in[10];

  float* wsf = (float*)d_ws;
  ushort* slabA = (ushort*)(wsf + OFF_SLABS);
  ushort* slabB = slabA + (size_t)16384*256;

  init_kernel  <<<1, 64, 0, stream>>>((int*)d_ws);
  detect_kernel<<<16, 256, 0, stream>>>((int*)d_ws, (const ushort*)W_ih);
  z1_kernel    <<<4, 256, 0, stream>>>(wsf, W_ih, b_ih, b_hh, bt, linit);
  prep_kernel  <<<512, 256, 0, stream>>>(wsf, W_ih, W_hh, Wc, Wt);
  ewc_kernel   <<<NVOCAB, 256, 0, stream>>>(wsf, Wc, bc, emb);
  h1_kernel    <<<1, 256, 0, stream>>>(wsf);
  hh1_kernel   <<<5, 256, 0, stream>>>(wsf, W_hh, Wc);
  table_kernel <<<NVOCAB, 256, 0, stream>>>(wsf, Wt, W_ih);

  // levels 7..0 ; idents offsets (4^l-1)/3
  level_kernel<true ,false><<<1024,256,0,stream>>>(wsf, nullptr, idents, 5461, 21845, 16384, slabA, nullptr);
  level_kernel<false,false><<<256 ,256,0,stream>>>(wsf, slabA,   idents, 1365, 0,     4096,  slabB, nullptr);
  level_kernel<false,false><<<64  ,256,0,stream>>>(wsf, slabB,   idents, 341,  0,     1024,  slabA, nullptr);
  level_kernel<false,false><<<16  ,256,0,stream>>>(wsf, slabA,   idents, 85,   0,     256,   slabB, nullptr);
  level_kernel<false,false><<<4   ,256,0,stream>>>(wsf, slabB,   idents, 21,   0,     64,    slabA, nullptr);
  level_kernel<false,false><<<1   ,256,0,stream>>>(wsf, slabA,   idents, 5,    0,     16,    slabB, nullptr);
  level_kernel<false,false><<<1   ,256,0,stream>>>(wsf, slabB,   idents, 1,    0,     4,     slabA, nullptr);
  level_kernel<false,true ><<<1   ,256,0,stream>>>(wsf, slabA,   idents, 0,    0,     1,     nullptr, d_out);
}